// Round 14
// baseline (91.030 us; speedup 1.0000x reference)
//
#include <hip/hip_runtime.h>
#include <hip/hip_fp16.h>

#define LSIDE 128
#define NB 16

union P8 { __half h[8]; int4 v; };

// packed8[z][y][x] = fp16 {v000,v001,v010,v011,v100,v101,v110,v111}
// corner pairs: x-pair innermost, then y, then z; edges clamped.
// Each thread packs 2 cells split across z-halves (both stores coalesced).
__global__ __launch_bounds__(256) void pack8_kernel(
    const float* __restrict__ vol, int4* __restrict__ packed)
{
    const int t0 = blockIdx.x * 256 + threadIdx.x;  // 0 .. 128^3/2-1
    #pragma unroll
    for (int c = 0; c < 2; ++c) {
        const int t = t0 + c * (LSIDE * LSIDE * LSIDE / 2);
        const int x = t & 127;
        const int y = (t >> 7) & 127;
        const int z = t >> 14;
        const int xp = min(x + 1, 127);
        const int yp = min(y + 1, 127);
        const int zp = min(z + 1, 127);
        const float* p00 = vol + (z  * LSIDE + y ) * LSIDE;
        const float* p01 = vol + (z  * LSIDE + yp) * LSIDE;
        const float* p10 = vol + (zp * LSIDE + y ) * LSIDE;
        const float* p11 = vol + (zp * LSIDE + yp) * LSIDE;
        P8 o;
        o.h[0] = __float2half(p00[x]); o.h[1] = __float2half(p00[xp]);
        o.h[2] = __float2half(p01[x]); o.h[3] = __float2half(p01[xp]);
        o.h[4] = __float2half(p10[x]); o.h[5] = __float2half(p10[xp]);
        o.h[6] = __float2half(p11[x]); o.h[7] = __float2half(p11[xp]);
        packed[t] = o.v;
    }
}

__device__ __forceinline__ void clip1(float r, float c, float A, float B,
                                      float& lo, float& hi)
{
    if (fabsf(r) > 1e-12f) {
        const float inv = 1.0f / r;
        const float a = (A - c) * inv, e = (B - c) * inv;
        lo = fmaxf(lo, fminf(a, e));
        hi = fminf(hi, fmaxf(a, e));
    } else if (c < A || c > B) {
        lo = 1e9f; hi = -1e9f;
    }
}

// per-axis clamped-cell weight fixup (zeros padding semantics)
__device__ __forceinline__ void axis_fix(float g, int& c, float& w0, float& w1)
{
    const float f = floorf(g);
    const int x0 = (int)f;
    const float t1 = g - f;
    const float t0 = 1.0f - t1;
    w0 = ((unsigned)x0 <= 127u) ? t0 : ((x0 == -1) ? t1 : 0.0f);
    w1 = ((unsigned)x0 <= 126u) ? t1 : 0.0f;
    c = min(max(x0, 0), LSIDE - 1);
}

__global__ __launch_bounds__(256) void ProjectorMultiRes_59236188947236_kernel(
    const float* __restrict__ rotmat,
    const int4* __restrict__ packed,
    const float* __restrict__ coords,
    float* __restrict__ out)
{
    const int tid  = threadIdx.x;
    const int wid  = tid >> 6;       // wave 0..3
    const int lane = tid & 63;
    const int g    = lane >> 3;      // pixel group 0..7 within wave
    const int l    = lane & 7;       // k-slot 0..7 within group

    // 8192 blocks; XCD-contiguous: XCD x gets logical [x*1024,(x+1)*1024) = 2 poses
    const int logical = (blockIdx.x & 7) * 1024 + (blockIdx.x >> 3);
    const int b   = logical >> 9;            // pose (512 blocks per pose)
    const int rem = logical & 511;
    const int i   = rem >> 2;                // row
    const int jc  = rem & 3;                 // 32-col chunk
    const int j   = jc * 32 + wid * 8 + g;   // pixel column

    const float* R = rotmat + b * 9;
    const float r00 = R[0], r01 = R[1], r02 = R[2];
    const float r10 = R[3], r11 = R[4], r12 = R[5];
    const float r20 = R[6], r21 = R[7], r22 = R[8];

    const float lj = coords[3 * j + 2];      // lin[j]
    const float li = coords[3 * i + 2];      // lin[i]
    const float bx = lj * r00 + li * r10;
    const float by = lj * r01 + li * r11;
    const float bz = lj * r02 + li * r12;

    const float h = 2.0f / 127.0f;

    // valid-k interval: any-contribution samples (index in [-0.02, 127.02])
    const float Bd = 1.0f + 1.0f / 63.5f + 1e-4f;
    float lo = -1.0f, hi = 1.0f;
    clip1(r20, bx, -Bd, Bd, lo, hi);
    clip1(r21, by, -Bd, Bd, lo, hi);
    clip1(r22, bz, -Bd, Bd, lo, hi);
    int k0 = max((int)ceilf((lo + 1.0f) / h) - 1, 0);
    int k1 = min((int)floorf((hi + 1.0f) / h) + 2, LSIDE);
    if (k1 < k0) k1 = k0;

    const float dxg = h * r20 * 63.5f;
    const float dyg = h * r21 * 63.5f;
    const float dzg = h * r22 * 63.5f;
    const float sdx = 8.0f * dxg, sdy = 8.0f * dyg, sdz = 8.0f * dzg;

    int k = k0 + l;                          // this lane's k-slots: k0+l, +8, +16, ...
    const float lk = fmaf((float)k, h, -1.0f);
    float gx = fmaf(lk, r20, bx) * 63.5f + 63.5f;
    float gy = fmaf(lk, r21, by) * 63.5f + 63.5f;
    float gz = fmaf(lk, r22, bz) * 63.5f + 63.5f;

    float acc = 0.0f;

    #pragma unroll 4
    for (; k < k1; k += 8) {
        int cx, cy, cz;
        float w0x, w1x, w0y, w1y, w0z, w1z;
        axis_fix(gx, cx, w0x, w1x);
        axis_fix(gy, cy, w0y, w1y);
        axis_fix(gz, cz, w0z, w1z);

        P8 c;
        c.v = packed[(cz * LSIDE + cy) * LSIDE + cx];
        gx += sdx; gy += sdy; gz += sdz;

        const float v000 = __half2float(c.h[0]);
        const float v001 = __half2float(c.h[1]);
        const float v010 = __half2float(c.h[2]);
        const float v011 = __half2float(c.h[3]);
        const float v100 = __half2float(c.h[4]);
        const float v101 = __half2float(c.h[5]);
        const float v110 = __half2float(c.h[6]);
        const float v111 = __half2float(c.h[7]);
        acc += ((v000 * w0x + v001 * w1x) * w0y + (v010 * w0x + v011 * w1x) * w1y) * w0z
             + ((v100 * w0x + v101 * w1x) * w0y + (v110 * w0x + v111 * w1x) * w1y) * w1z;
    }

    // reduce the 8 k-slots of each pixel group
    acc += __shfl_down(acc, 4, 8);
    acc += __shfl_down(acc, 2, 8);
    acc += __shfl_down(acc, 1, 8);
    if (l == 0)
        out[(b * LSIDE + i) * LSIDE + j] = acc;
}

extern "C" void kernel_launch(void* const* d_in, const int* in_sizes, int n_in,
                              void* d_out, int out_size, void* d_ws, size_t ws_size,
                              hipStream_t stream) {
    const float* rotmat = (const float*)d_in[0];
    const float* vol    = (const float*)d_in[1];
    const float* coords = (const float*)d_in[2];
    float* out = (float*)d_out;

    int4* packed = (int4*)d_ws;
    pack8_kernel<<<(LSIDE * LSIDE * LSIDE / 2) / 256, 256, 0, stream>>>(vol, packed);
    ProjectorMultiRes_59236188947236_kernel<<<NB * LSIDE * LSIDE / 32, 256, 0, stream>>>(
        rotmat, packed, coords, out);
}

// Round 15
// 86.964 us; speedup vs baseline: 1.0467x; 1.0467x over previous
//
#include <hip/hip_runtime.h>
#include <hip/hip_fp16.h>

#define LSIDE 128
#define NB 16

union P8 { __half h[8]; int4 v; };

// packed8[z][y][x] = fp16 {v000,v001,v010,v011,v100,v101,v110,v111}
// corner pairs: x-pair innermost, then y, then z; edges clamped.
// Each thread packs 2 cells split across z-halves (both stores coalesced).
__global__ __launch_bounds__(256) void pack8_kernel(
    const float* __restrict__ vol, int4* __restrict__ packed)
{
    const int t0 = blockIdx.x * 256 + threadIdx.x;  // 0 .. 128^3/2-1
    #pragma unroll
    for (int c = 0; c < 2; ++c) {
        const int t = t0 + c * (LSIDE * LSIDE * LSIDE / 2);
        const int x = t & 127;
        const int y = (t >> 7) & 127;
        const int z = t >> 14;
        const int xp = min(x + 1, 127);
        const int yp = min(y + 1, 127);
        const int zp = min(z + 1, 127);
        const float* p00 = vol + (z  * LSIDE + y ) * LSIDE;
        const float* p01 = vol + (z  * LSIDE + yp) * LSIDE;
        const float* p10 = vol + (zp * LSIDE + y ) * LSIDE;
        const float* p11 = vol + (zp * LSIDE + yp) * LSIDE;
        P8 o;
        o.h[0] = __float2half(p00[x]); o.h[1] = __float2half(p00[xp]);
        o.h[2] = __float2half(p01[x]); o.h[3] = __float2half(p01[xp]);
        o.h[4] = __float2half(p10[x]); o.h[5] = __float2half(p10[xp]);
        o.h[6] = __float2half(p11[x]); o.h[7] = __float2half(p11[xp]);
        packed[t] = o.v;
    }
}

__device__ __forceinline__ void clip1(float r, float c, float A, float B,
                                      float& lo, float& hi)
{
    if (fabsf(r) > 1e-12f) {
        const float inv = 1.0f / r;
        const float a = (A - c) * inv, e = (B - c) * inv;
        lo = fmaxf(lo, fminf(a, e));
        hi = fminf(hi, fmaxf(a, e));
    } else if (c < A || c > B) {
        lo = 1e9f; hi = -1e9f;
    }
}

// per-axis clamped-cell weight fixup (zeros padding semantics)
__device__ __forceinline__ void axis_fix(float g, int& c, float& w0, float& w1)
{
    const float f = floorf(g);
    const int x0 = (int)f;
    const float t1 = g - f;
    const float t0 = 1.0f - t1;
    w0 = ((unsigned)x0 <= 127u) ? t0 : ((x0 == -1) ? t1 : 0.0f);
    w1 = ((unsigned)x0 <= 126u) ? t1 : 0.0f;
    c = min(max(x0, 0), LSIDE - 1);
}

__global__ __launch_bounds__(256) void ProjectorMultiRes_59236188947236_kernel(
    const float* __restrict__ rotmat,
    const int4* __restrict__ packed,
    const float* __restrict__ coords,
    float* __restrict__ out)
{
    const int tid  = threadIdx.x;
    const int wid  = tid >> 6;       // wave 0..3
    const int lane = tid & 63;
    const int g    = lane >> 3;      // pixel group 0..7 within wave
    const int l    = lane & 7;       // k-slot 0..7 within group

    // 8192 blocks; XCD-contiguous: XCD x gets logical [x*1024,(x+1)*1024) = 2 poses
    const int logical = (blockIdx.x & 7) * 1024 + (blockIdx.x >> 3);
    const int b   = logical >> 9;            // pose (512 blocks per pose)
    const int rem = logical & 511;
    const int i   = rem >> 2;                // row
    const int jc  = rem & 3;                 // 32-col chunk
    const int j   = jc * 32 + wid * 8 + g;   // pixel column

    const float* R = rotmat + b * 9;
    const float r00 = R[0], r01 = R[1], r02 = R[2];
    const float r10 = R[3], r11 = R[4], r12 = R[5];
    const float r20 = R[6], r21 = R[7], r22 = R[8];

    const float lj = coords[3 * j + 2];      // lin[j]
    const float li = coords[3 * i + 2];      // lin[i]
    const float bx = lj * r00 + li * r10;
    const float by = lj * r01 + li * r11;
    const float bz = lj * r02 + li * r12;

    const float h = 2.0f / 127.0f;

    // valid-k interval: any-contribution samples (index in [-0.02, 127.02])
    const float Bd = 1.0f + 1.0f / 63.5f + 1e-4f;
    float lo = -1.0f, hi = 1.0f;
    clip1(r20, bx, -Bd, Bd, lo, hi);
    clip1(r21, by, -Bd, Bd, lo, hi);
    clip1(r22, bz, -Bd, Bd, lo, hi);
    int k0 = max((int)ceilf((lo + 1.0f) / h) - 1, 0);
    int k1 = min((int)floorf((hi + 1.0f) / h) + 2, LSIDE);
    if (k1 < k0) k1 = k0;

    const float dxg = h * r20 * 63.5f;
    const float dyg = h * r21 * 63.5f;
    const float dzg = h * r22 * 63.5f;
    const float sdx = 8.0f * dxg, sdy = 8.0f * dyg, sdz = 8.0f * dzg;

    int k = k0 + l;                          // this lane's k-slots: k0+l, +8, +16, ...
    const float lk = fmaf((float)k, h, -1.0f);
    float gx = fmaf(lk, r20, bx) * 63.5f + 63.5f;
    float gy = fmaf(lk, r21, by) * 63.5f + 63.5f;
    float gz = fmaf(lk, r22, bz) * 63.5f + 63.5f;

    float acc = 0.0f;

    #pragma unroll 2
    for (; k < k1; k += 8) {
        int cx, cy, cz;
        float w0x, w1x, w0y, w1y, w0z, w1z;
        axis_fix(gx, cx, w0x, w1x);
        axis_fix(gy, cy, w0y, w1y);
        axis_fix(gz, cz, w0z, w1z);

        P8 c;
        c.v = packed[(cz * LSIDE + cy) * LSIDE + cx];
        gx += sdx; gy += sdy; gz += sdz;

        const float v000 = __half2float(c.h[0]);
        const float v001 = __half2float(c.h[1]);
        const float v010 = __half2float(c.h[2]);
        const float v011 = __half2float(c.h[3]);
        const float v100 = __half2float(c.h[4]);
        const float v101 = __half2float(c.h[5]);
        const float v110 = __half2float(c.h[6]);
        const float v111 = __half2float(c.h[7]);
        acc += ((v000 * w0x + v001 * w1x) * w0y + (v010 * w0x + v011 * w1x) * w1y) * w0z
             + ((v100 * w0x + v101 * w1x) * w0y + (v110 * w0x + v111 * w1x) * w1y) * w1z;
    }

    // reduce the 8 k-slots of each pixel group
    acc += __shfl_down(acc, 4, 8);
    acc += __shfl_down(acc, 2, 8);
    acc += __shfl_down(acc, 1, 8);
    if (l == 0)
        out[(b * LSIDE + i) * LSIDE + j] = acc;
}

extern "C" void kernel_launch(void* const* d_in, const int* in_sizes, int n_in,
                              void* d_out, int out_size, void* d_ws, size_t ws_size,
                              hipStream_t stream) {
    const float* rotmat = (const float*)d_in[0];
    const float* vol    = (const float*)d_in[1];
    const float* coords = (const float*)d_in[2];
    float* out = (float*)d_out;

    int4* packed = (int4*)d_ws;
    pack8_kernel<<<(LSIDE * LSIDE * LSIDE / 2) / 256, 256, 0, stream>>>(vol, packed);
    ProjectorMultiRes_59236188947236_kernel<<<NB * LSIDE * LSIDE / 32, 256, 0, stream>>>(
        rotmat, packed, coords, out);
}